// Round 15
// baseline (209.981 us; speedup 1.0000x reference)
//
#include <hip/hip_runtime.h>
#include <hip/hip_bf16.h>

// SelfAttention: x[2,2048,1024] fp32; w_qkv[3072,1024]; w_out[1024,1024]; b_out[1024]
// Pipeline:
//  (0) cvt_all: x, w_qkv (q rows pre-scaled by 0.125*log2e), w_out -> bf16 ws
//  (1) gemm128<0,128,3>: qkv = x @ w_qkv^T. q,k -> qk_ws bf16 [4096,2048];
//      v -> vt_ws transposed [b][h][d][key].  XCD-swizzled blocks.
//  (2) attn_kernel: r11 pipeline, 128-key chunks. Wave w stages tile w of
//      {K0,K1,V0,V1} (64x72 pitch = conflict-free); lane = FULL row =
//      8 x b128 loads + 8 x b128 ds_writes (r14 bug: only 4 -> half tile
//      uninitialized -> NaN). Half the barriers of r11. Inner body x2 per
//      chunk (hh = 64-key tile) = r11 verbatim.
//  (3) gemm128<1,64,2>: out = attn @ w_out^T + b_out.  XCD-swizzled blocks.
// GEMM: BM=128, BK=64, global_load_lds w=16, XOR-swizzle (2-way banks, free).
// 32x32 C/D layout: col=lane&31 (B's n), row=(reg&3)+8*(reg>>2)+4*(lane>>5).
// 32x32 A/B frag: lane&31 = m/n, k = (lane>>5)*8 + j (8 contiguous bf16 = 16 B).
// NOTE (journal): attn experiments r8 (LDS dbuf, 67.5), r9 (LDS-free, 134),
// r10 (gl2lds dbuf, 68.6), r12 (512-thr blocks, 66.9), r13 (key-split, 69.8)
// all regressed vs r7/r11 (61 us). r14: staging-volume NaN (half-row bug).

#define SEQ   2048
#define BATCH 2
#define CDIM  1024
#define NH    16
#define HD    64
#define NTOK  (BATCH*SEQ)
#define QSCALE 0.18033688011f   // 0.125 * log2(e)

typedef __attribute__((ext_vector_type(8)))  short s16x8;
typedef __attribute__((ext_vector_type(4)))  float f32x4;
typedef __attribute__((ext_vector_type(16))) float f32x16;
typedef __attribute__((ext_vector_type(4)))  unsigned u32x4;
typedef __attribute__((ext_vector_type(2)))  __bf16 bf16x2;

__device__ __forceinline__ short f2bf(float x) {
  unsigned u = __builtin_bit_cast(unsigned, x);
  u = (u + 0x7fffu + ((u >> 16) & 1u)) >> 16;
  return (short)u;
}

// pack two fp32 -> bf16x2 in one u32 (low=a, high=b)
__device__ __forceinline__ unsigned f2bf2(float a, float b) {
#if __has_builtin(__builtin_amdgcn_cvt_pk_bf16_f32)
  bf16x2 v = __builtin_amdgcn_cvt_pk_bf16_f32(a, b);
  return __builtin_bit_cast(unsigned, v);
#else
  unsigned ua = __builtin_bit_cast(unsigned, a) + 0x8000u;
  unsigned ub = __builtin_bit_cast(unsigned, b) + 0x8000u;
  return (ub & 0xffff0000u) | (ua >> 16);
#endif
}

__device__ __forceinline__ float exp2_fast(float x) {
  return __builtin_amdgcn_exp2f(x);   // v_exp_f32
}

__device__ __forceinline__ void gl2lds16(const short* g, short* l) {
  __builtin_amdgcn_global_load_lds(
      (const __attribute__((address_space(1))) void*)g,
      (__attribute__((address_space(3))) void*)l, 16, 0, 0);
}

// ---------------------------------------------------------------------------
// Fused fp32 -> bf16 converts (x | w_qkv(q-scaled) | w_out), 2048 elem/block.
// ---------------------------------------------------------------------------
__global__ __launch_bounds__(256) void cvt_all(
    const float* __restrict__ x, const float* __restrict__ wqkv,
    const float* __restrict__ wout, short* __restrict__ x_bf,
    short* __restrict__ wqkv_bf, short* __restrict__ wout_bf)
{
  int blk = blockIdx.x;
  const float* src; short* dst; int base; float scale = 1.0f;
  if (blk < 2048)      { src = x;    dst = x_bf;    base = blk; }
  else if (blk < 3584) { src = wqkv; dst = wqkv_bf; base = blk - 2048;
                         if (base < 512) scale = QSCALE; }  // q rows
  else                 { src = wout; dst = wout_bf; base = blk - 3584; }
  size_t i = ((size_t)base * 256 + threadIdx.x) * 8;
  float4 v0 = *(const float4*)(src + i);
  float4 v1 = *(const float4*)(src + i + 4);
  s16x8 p;
  p[0]=f2bf(v0.x*scale); p[1]=f2bf(v0.y*scale); p[2]=f2bf(v0.z*scale); p[3]=f2bf(v0.w*scale);
  p[4]=f2bf(v1.x*scale); p[5]=f2bf(v1.y*scale); p[6]=f2bf(v1.z*scale); p[7]=f2bf(v1.w*scale);
  *(s16x8*)(dst + i) = p;
}

// ---------------------------------------------------------------------------
// GEMM: C[M,N] = A[M,K] @ B[N,K]^T, bf16. BM=128, BK=64, 4 waves, 256 thr.
// BN=128: wave 64x64 acc[4][4]; BN=64: wave 64x32 acc[4][2].
// 1-D grid, XCD-swizzled: xcd = id&7 owns BXW consecutive B-panels.
// LDS [rows][64] shorts; 16B chunk at (row,pos) holds global chunk
// pos ^ (row&7); frag reads hit bank-group quad^(lrow&7) -> 2-way (free).
// MODE 0: QKV epilogue (q,k -> qk bf16 pitch 2048; v -> vt transposed).
// MODE 1: fp32 + bias epilogue.
// ---------------------------------------------------------------------------
template<int MODE, int BN, int BXW>
__global__ __launch_bounds__(256) void gemm128(
    const short* __restrict__ A, const short* __restrict__ B,
    const float* __restrict__ bias, void* __restrict__ Cp,
    short* __restrict__ vt, int M, int N, int K)
{
  constexpr int TN = BN / 32;     // acc tiles per wave in N (4 or 2)
  constexpr int NB = BN / 32;     // B-staging gl2lds per thread (4 or 2)

  __shared__ __align__(16) short As[128 * 64];
  __shared__ __align__(16) short Bs[BN * 64];

  const int t    = threadIdx.x;
  const int w    = t >> 6, lane = t & 63;
  const int id   = blockIdx.x;
  const int xcd  = id & 7, ii = id >> 3;
  const int bm   = (ii / BXW) * 128;
  const int bn   = (xcd * BXW + ii % BXW) * BN;
  const int wm   = (w >> 1) * 64, wn = (w & 1) * (BN / 2);
  const int lrow = lane & 15, quad = lane >> 4;

  int goffA[4], goffB[NB];
#pragma unroll
  for (int i = 0; i < 4; i++) {
    int L   = (w * 4 + i) * 64 + lane;     // 16B-chunk index in 128x64 tile
    int row = L >> 3, pos = L & 7;
    int src = pos ^ (row & 7);
    goffA[i] = (bm + row) * K + src * 8;
  }
#pragma unroll
  for (int i = 0; i < NB; i++) {
    int L   = (w * NB + i) * 64 + lane;
    int row = L >> 3, pos = L & 7;
    int src = pos ^ (row & 7);
    goffB[i] = (bn + row) * K + src * 8;
  }
  const int fk0 = (quad ^ (lrow & 7)) * 8;
  const int fk1 = fk0 ^ 32;

  f32x4 acc[4][TN];
#pragma unroll
  for (int i = 0; i < 4; i++)
#pragma unroll
    for (int j = 0; j < TN; j++) acc[i][j] = (f32x4){0.f, 0.f, 0.f, 0.f};

  for (int k0 = 0; k0 < K; k0 += 64) {
    __syncthreads();
#pragma unroll
    for (int i = 0; i < 4; i++)
      gl2lds16(A + goffA[i] + k0, &As[(w * 4 + i) * 512]);
#pragma unroll
    for (int i = 0; i < NB; i++)
      gl2lds16(B + goffB[i] + k0, &Bs[(w * NB + i) * 512]);
    __syncthreads();

    s16x8 a[4][2], b[TN][2];
#pragma unroll
    for (int tm = 0; tm < 4; tm++) {
      a[tm][0] = *(const s16x8*)&As[(wm + tm * 16 + lrow) * 64 + fk0];
      a[tm][1] = *(const s16x8*)&As[(wm + tm * 16 + lrow) * 64 + fk1];
    }
#pragma unroll
    for (int tn = 0; tn < TN; tn++) {
      b[tn][0] = *(const s16x8*)&Bs[(wn + tn * 16 + lrow) * 64 + fk0];
      b[tn][1] = *(const s16x8*)&Bs[(wn + tn * 16 + lrow) * 64 + fk1];
    }
#pragma unroll
    for (int hh = 0; hh < 2; hh++)
#pragma unroll
      for (int tm = 0; tm < 4; tm++)
#pragma unroll
        for (int tn = 0; tn < TN; tn++)
          acc[tm][tn] = __builtin_amdgcn_mfma_f32_16x16x32_bf16(
              a[tm][hh], b[tn][hh], acc[tm][tn], 0, 0, 0);
  }

  if (MODE == 1) {
#pragma unroll
    for (int tm = 0; tm < 4; tm++)
#pragma unroll
      for (int tn = 0; tn < TN; tn++)
#pragma unroll
        for (int i = 0; i < 4; i++) {
          int row = bm + wm + tm * 16 + quad * 4 + i;
          int col = bn + wn + tn * 16 + lrow;
          ((float*)Cp)[(size_t)row * N + col] = acc[tm][tn][i] + bias[col];
        }
  } else if (bn < 2 * CDIM) {
#pragma unroll
    for (int tm = 0; tm < 4; tm++)
#pragma unroll
      for (int tn = 0; tn < TN; tn++)
#pragma unroll
        for (int i = 0; i < 4; i++) {
          int row = bm + wm + tm * 16 + quad * 4 + i;
          int col = bn + wn + tn * 16 + lrow;
          ((short*)Cp)[(size_t)row * 2048 + col] = f2bf(acc[tm][tn][i]);
        }
  } else {
#pragma unroll
    for (int tm = 0; tm < 4; tm++)
#pragma unroll
      for (int tn = 0; tn < TN; tn++) {
        int vcol = bn - 2 * CDIM + wn + tn * 16 + lrow;
        int h    = vcol >> 6, d = vcol & 63;
        int r0   = bm + wm + tm * 16 + quad * 4;
        int bb   = r0 >> 11, key = r0 & (SEQ - 1);
        size_t off = (((size_t)(bb * NH + h) * HD + d) << 11) + key;
        uint2 pk;
        pk.x = f2bf2(acc[tm][tn][0], acc[tm][tn][1]);
        pk.y = f2bf2(acc[tm][tn][2], acc[tm][tn][3]);
        *(uint2*)(vt + off) = pk;
      }
  }
}

// ---------------------------------------------------------------------------
// Flash attention (r11 pipeline, 128-key chunks). 32x32x16 MFMA, 2x2 wave
// grid (wq=q-half, wk=key-half). Staging: wave w stages tile w of
// {K0,K1,V0,V1} (each 64 rows x pitch 72 = conflict-free); lane = one FULL
// row = 8 b128 loads + 8 b128 ds_writes (64 shorts). Prefetch: 8 s16x8/thr.
// 2 barriers per 128 keys (half of r11). Inner body x2 (hh = 64-key tile):
// S^T = mfma(K, Q regs); no-max softmax (exp2, scale pre-folded); C->A via
// shfl_xor(32) in regs; PV from Vs[d][key]. End: cross-wk O/l reduce via LDS.
// ---------------------------------------------------------------------------
__global__ __launch_bounds__(256) void attn_kernel(
    const short* __restrict__ qk, const short* __restrict__ vt,
    short* __restrict__ attn_out)
{
  __shared__ __align__(16) short smem[4 * 64 * 72];   // K0|K1|V0|V1, 36,864 B

  const int t   = threadIdx.x;
  const int w   = t >> 6, lane = t & 63;
  const int l31 = lane & 31, h = lane >> 5;
  const int wq  = w & 1, wk = w >> 1;
  const int bh  = blockIdx.x;
  const int b   = bh >> 4, hd = bh & (NH - 1);
  const int q0  = blockIdx.y * 64;

  const short* base  = qk + (size_t)(b * SEQ) * 2048 + hd * HD;
  const short* vbase = vt + ((size_t)(b * NH + hd) * HD) * SEQ;

  // Q B-frags in registers (pre-scaled): n=q, k=d=c*16+h*8+j
  s16x8 qf[4];
  {
    const short* qp = base + (size_t)(q0 + wq * 32 + l31) * 2048;
#pragma unroll
    for (int c = 0; c < 4; c++) qf[c] = *(const s16x8*)(qp + c * 16 + h * 8);
  }

  f32x16 o0 = {}, o1 = {};
  float lsum = 0.f;

  // staging: wave w owns tile w; lane = full row (64 shorts = 8 x b128)
  const short* gs;
  size_t gstep;
  if (w < 2) { gs = base + CDIM + (size_t)(w * 64 + lane) * 2048;
               gstep = (size_t)128 * 2048; }
  else       { gs = vbase + (size_t)lane * SEQ + (w - 2) * 64;
               gstep = 128; }
  short* ld = smem + w * 4608 + lane * 72;

  // prefetch chunk 0 into registers (8 s16x8 = full row)
  s16x8 pr[8];
#pragma unroll
  for (int i = 0; i < 8; i++) pr[i] = *(const s16x8*)(gs + i * 8);

  for (int it = 0; it < SEQ / 128; it++) {
    __syncthreads();                          // prior chunk's frag reads done
#pragma unroll
    for (int i = 0; i < 8; i++) *(s16x8*)(ld + i * 8) = pr[i];
    __syncthreads();                          // tiles ready

    // issue next chunk's loads (overlap with compute below)
    {
      const short* g = gs + (size_t)((it + 1 < SEQ / 128) ? it + 1 : it) * gstep;
#pragma unroll
      for (int i = 0; i < 8; i++) pr[i] = *(const s16x8*)(g + i * 8);
    }

#pragma unroll
    for (int hh = 0; hh < 2; hh++) {
      const short* Ks = smem + hh * 4608;
      const short* Vs = smem + (2 + hh) * 4608;

      // S^T[key][q]: A = K rows (wk half), B = Q regs
      f32x16 s = {};
#pragma unroll
      for (int c = 0; c < 4; c++) {
        s16x8 kf = *(const s16x8*)&Ks[(wk * 32 + l31) * 72 + c * 16 + h * 8];
        s = __builtin_amdgcn_mfma_f32_32x32x16_bf16(kf, qf[c], s, 0, 0, 0);
      }

      // softmax + pack: reg r -> key (r&3)+8*(r>>2)+4h (local to wave's half)
      uint2 pg[4];
#pragma unroll
      for (int g = 0; g < 4; g++) {
        float e0 = exp2_fast(s[4 * g + 0]);
        float e1 = exp2_fast(s[4 * g + 1]);
        float e2 = exp2_fast(s[4 * g + 2]);
        float e3 = exp2_fast(s[4 * g + 3]);
        lsum += (e0 + e1) + (e2 + e3);
        pg[g].x = f2bf2(e0, e1);
        pg[g].y = f2bf2(e2, e3);
      }

      // C->A: per 16-key chunk kc2, swap 4-key groups between lane<->lane+32
      s16x8 pf[2];
#pragma unroll
      for (int kc2 = 0; kc2 < 2; kc2++) {
        uint2 send = h ? pg[2 * kc2] : pg[2 * kc2 + 1];
        uint2 recv;
        recv.x = (unsigned)__shfl_xor((int)send.x, 32);
        recv.y = (unsigned)__shfl_xor((int)send.y, 32);
        uint2 lo = h ? recv : pg[2 * kc2];
        uint2 hi = h ? pg[2 * kc2 + 1] : recv;
        u32x4 f = {lo.x, lo.y, hi.x, hi.y};
        pf[kc2] = __builtin_bit_cast(s16x8, f);
      }

      // PV: O[q][d] += P * V over wave's 32 keys; B-frag from Vs[d][key]
#pragma unroll
      for (int kc2 = 0; kc2 < 2; kc2++) {
        s16x8 v0 = *(const s16x8*)&Vs[l31 * 72        + wk * 32 + kc2 * 16 + h * 8];
        s16x8 v1 = *(const s16x8*)&Vs[(32 + l31) * 72 + wk * 32 + kc2 * 16 + h * 8];
        o0 = __builtin_amdgcn_mfma_f32_32x32x16_bf16(pf[kc2], v0, o0, 0, 0, 0);
        o1 = __builtin_amdgcn_mfma_f32_32x32x16_bf16(pf[kc2], v1, o1, 0, 0, 0);
      }
    }
  }

  // ---- epilogue: cross-wk reduction of O and l, normalize, store ----
  lsum += __shfl_xor(lsum, 32);          // combine h halves (disjoint keys)

  float* Ored = (float*)smem;            // [2 wq][32 q][64 d] = 16 KB
  float* Lred = (float*)smem + 4096;     // [64]

  __syncthreads();                       // drain last chunk's LDS reads
  if (wk == 0) {
#pragma unroll
    for (int r = 0; r < 16; r++) {
      int ql = (r & 3) + 8 * (r >> 2) + 4 * h;
      Ored[(wq * 32 + ql) * 64 + l31]      = o0[r];
      Ored[(wq * 32 + ql) * 64 + 32 + l31] = o1[r];
    }
    if (lane < 32) Lred[wq * 32 + l31] = lsum;
  }
  __syncthreads();
  if (wk == 1 && lane < 32) Lred[wq * 32 + l31] += lsum;
  __syncthreads();
  if (wk == 1) {
#pragma unroll
    for (int r = 0; r < 16; r++) {
      int ql = (r & 3) + 8 * (r >> 2) + 4 * h;
      float linv = 1.0f / Lred[wq * 32 + ql];
      int qg = q0 + wq * 32 + ql;
      size_t rowb = (size_t)(b * SEQ + qg) * CDIM + hd * HD;
      float v0 = (o0[r] + Ored[(wq * 32 + ql) * 64 + l31]) * linv;
      float v1 = (o1[r] + Ored[(wq * 32 + ql) * 64 + 32 + l31]) * linv;
      attn_out[rowb + l31]      = f2bf(v0);
      attn_out[rowb + 32 + l31] = f2bf(v1);
    }
  }
}

// ---------------------------------------------------------------------------
extern "C" void kernel_launch(void* const* d_in, const int* in_sizes, int n_in,
                              void* d_out, int out_size, void* d_ws, size_t ws_size,
                              hipStream_t stream)
{
  const float* x     = (const float*)d_in[0];
  const float* w_qkv = (const float*)d_in[1];
  const float* w_out = (const float*)d_in[2];
  const float* b_out = (const float*)d_in[3];

  short* qk_ws   = (short*)d_ws;                         // 4096*2048 = 16 MB
  short* vt_ws   = qk_ws  + (size_t)NTOK * 2048;         // 4096*1024 =  8 MB
  short* x_bf    = vt_ws  + (size_t)NTOK * CDIM;         // 4096*1024 =  8 MB
  short* attn_ws = x_bf;                                 // alias (x_bf dead)
  short* wqkv_bf = x_bf   + (size_t)NTOK * CDIM;         // 3072*1024 =  6 MB
  short* wout_bf = wqkv_bf + (size_t)3 * CDIM * CDIM;    // 1024*1024 =  2 MB

  dim3 blk(256);

  cvt_all<<<dim3(4096), blk, 0, stream>>>(x, w_qkv, w_out, x_bf, wqkv_bf, wout_bf);

  // (1) qkv: 768 blocks, 1-D XCD-swizzled (3 B-panels per XCD)
  gemm128<0, 128, 3><<<dim3(768), blk, 0, stream>>>(
      x_bf, wqkv_bf, nullptr, qk_ws, vt_ws, NTOK, 3 * CDIM, CDIM);

  attn_kernel<<<dim3(BATCH * NH, SEQ / 64), blk, 0, stream>>>(qk_ws, vt_ws, attn_ws);

  // (3) out: 512 blocks, 1-D XCD-swizzled (2 B-panels per XCD)
  gemm128<1, 64, 2><<<dim3(512), blk, 0, stream>>>(
      attn_ws, wout_bf, b_out, d_out, nullptr, NTOK, CDIM, CDIM);
}

// Round 16
// 188.779 us; speedup vs baseline: 1.1123x; 1.1123x over previous
//
#include <hip/hip_runtime.h>
#include <hip/hip_bf16.h>

// SelfAttention: x[2,2048,1024] fp32; w_qkv[3072,1024]; w_out[1024,1024]; b_out[1024]
// Pipeline (consolidated best-of-measured, r16):
//  (0) cvt_all: x, w_qkv (q rows pre-scaled by 0.125*log2e), w_out -> bf16 ws
//  (1) gemm128<0,128,3>: qkv = x @ w_qkv^T. q,k -> qk_ws bf16 [4096,2048];
//      v -> vt_ws transposed [b][h][d][key].  XCD-swizzled 1-D grid (r15, -10us).
//  (2) attn_kernel: r11 verbatim (best measured, 61 us): 32x32x16 MFMA,
//      2x2 wave grid (wq=q-half, wk=key-half), 64-key chunks, lane-quad
//      coalesced staging (4 lanes/row, 128B segments), pitch-72 LDS
//      (conflict-free), register prefetch, 2 barriers/chunk.
//      S^T = mfma(K, Q(regs)); C->A via shfl_xor(32) in regs (no P LDS
//      round-trip); no-max softmax (exp2, scale pre-folded into w_qkv q rows).
//  (3) gemm128<1,64,2>: out = attn @ w_out^T + b_out.  XCD-swizzled.
// GEMM: BM=128, BK=64, global_load_lds w=16, XOR-swizzle (2-way banks, free).
// 32x32 C/D layout: col=lane&31 (B's n), row=(reg&3)+8*(reg>>2)+4*(lane>>5).
// 32x32 A/B frag: lane&31 = m/n, k = (lane>>5)*8 + j (8 contiguous bf16 = 16 B).
// JOURNAL (attn experiments, all vs r7/r11 = 61 us):
//   r8 LDS-dbuf 67.5 | r9 LDS-free 134 | r10 gl2lds-dbuf 68.6 (pitch-128B ->
//   4-way conflicts) | r12 512-thr blocks 66.9 (barrier convoy) | r13
//   key-split fp32 partials 69.8 (HBM traffic) | r15 wide-chunk lane-per-row
//   98 (4KB-stride staging, 64 lines/instr). The r11 pipeline is the local
//   optimum: every perturbation that adds VGPR/LDS/HBM state or degrades
//   staging coalescing loses more than it gains.

#define SEQ   2048
#define BATCH 2
#define CDIM  1024
#define NH    16
#define HD    64
#define NTOK  (BATCH*SEQ)
#define QSCALE 0.18033688011f   // 0.125 * log2(e)

typedef __attribute__((ext_vector_type(8)))  short s16x8;
typedef __attribute__((ext_vector_type(4)))  float f32x4;
typedef __attribute__((ext_vector_type(16))) float f32x16;
typedef __attribute__((ext_vector_type(4)))  unsigned u32x4;
typedef __attribute__((ext_vector_type(2)))  __bf16 bf16x2;

__device__ __forceinline__ short f2bf(float x) {
  unsigned u = __builtin_bit_cast(unsigned, x);
  u = (u + 0x7fffu + ((u >> 16) & 1u)) >> 16;
  return (short)u;
}

// pack two fp32 -> bf16x2 in one u32 (low=a, high=b)
__device__ __forceinline__ unsigned f2bf2(float a, float b) {
#if __has_builtin(__builtin_amdgcn_cvt_pk_bf16_f32)
  bf16x2 v = __builtin_amdgcn_cvt_pk_bf16_f32(a, b);
  return __builtin_bit_cast(unsigned, v);
#else
  unsigned ua = __builtin_bit_cast(unsigned, a) + 0x8000u;
  unsigned ub = __builtin_bit_cast(unsigned, b) + 0x8000u;
  return (ub & 0xffff0000u) | (ua >> 16);
#endif
}

__device__ __forceinline__ float exp2_fast(float x) {
  return __builtin_amdgcn_exp2f(x);   // v_exp_f32
}

__device__ __forceinline__ void gl2lds16(const short* g, short* l) {
  __builtin_amdgcn_global_load_lds(
      (const __attribute__((address_space(1))) void*)g,
      (__attribute__((address_space(3))) void*)l, 16, 0, 0);
}

// ---------------------------------------------------------------------------
// Fused fp32 -> bf16 converts (x | w_qkv(q-scaled) | w_out), 2048 elem/block.
// ---------------------------------------------------------------------------
__global__ __launch_bounds__(256) void cvt_all(
    const float* __restrict__ x, const float* __restrict__ wqkv,
    const float* __restrict__ wout, short* __restrict__ x_bf,
    short* __restrict__ wqkv_bf, short* __restrict__ wout_bf)
{
  int blk = blockIdx.x;
  const float* src; short* dst; int base; float scale = 1.0f;
  if (blk < 2048)      { src = x;    dst = x_bf;    base = blk; }
  else if (blk < 3584) { src = wqkv; dst = wqkv_bf; base = blk - 2048;
                         if (base < 512) scale = QSCALE; }  // q rows
  else                 { src = wout; dst = wout_bf; base = blk - 3584; }
  size_t i = ((size_t)base * 256 + threadIdx.x) * 8;
  float4 v0 = *(const float4*)(src + i);
  float4 v1 = *(const float4*)(src + i + 4);
  s16x8 p;
  p[0]=f2bf(v0.x*scale); p[1]=f2bf(v0.y*scale); p[2]=f2bf(v0.z*scale); p[3]=f2bf(v0.w*scale);
  p[4]=f2bf(v1.x*scale); p[5]=f2bf(v1.y*scale); p[6]=f2bf(v1.z*scale); p[7]=f2bf(v1.w*scale);
  *(s16x8*)(dst + i) = p;
}

// ---------------------------------------------------------------------------
// GEMM: C[M,N] = A[M,K] @ B[N,K]^T, bf16. BM=128, BK=64, 4 waves, 256 thr.
// BN=128: wave 64x64 acc[4][4]; BN=64: wave 64x32 acc[4][2].
// 1-D grid, XCD-swizzled: xcd = id&7 owns BXW consecutive B-panels.
// LDS [rows][64] shorts; 16B chunk at (row,pos) holds global chunk
// pos ^ (row&7); frag reads hit bank-group quad^(lrow&7) -> 2-way (free).
// MODE 0: QKV epilogue (q,k -> qk bf16 pitch 2048; v -> vt transposed).
// MODE 1: fp32 + bias epilogue.
// ---------------------------------------------------------------------------
template<int MODE, int BN, int BXW>
__global__ __launch_bounds__(256) void gemm128(
    const short* __restrict__ A, const short* __restrict__ B,
    const float* __restrict__ bias, void* __restrict__ Cp,
    short* __restrict__ vt, int M, int N, int K)
{
  constexpr int TN = BN / 32;     // acc tiles per wave in N (4 or 2)
  constexpr int NB = BN / 32;     // B-staging gl2lds per thread (4 or 2)

  __shared__ __align__(16) short As[128 * 64];
  __shared__ __align__(16) short Bs[BN * 64];

  const int t    = threadIdx.x;
  const int w    = t >> 6, lane = t & 63;
  const int id   = blockIdx.x;
  const int xcd  = id & 7, ii = id >> 3;
  const int bm   = (ii / BXW) * 128;
  const int bn   = (xcd * BXW + ii % BXW) * BN;
  const int wm   = (w >> 1) * 64, wn = (w & 1) * (BN / 2);
  const int lrow = lane & 15, quad = lane >> 4;

  int goffA[4], goffB[NB];
#pragma unroll
  for (int i = 0; i < 4; i++) {
    int L   = (w * 4 + i) * 64 + lane;     // 16B-chunk index in 128x64 tile
    int row = L >> 3, pos = L & 7;
    int src = pos ^ (row & 7);
    goffA[i] = (bm + row) * K + src * 8;
  }
#pragma unroll
  for (int i = 0; i < NB; i++) {
    int L   = (w * NB + i) * 64 + lane;
    int row = L >> 3, pos = L & 7;
    int src = pos ^ (row & 7);
    goffB[i] = (bn + row) * K + src * 8;
  }
  const int fk0 = (quad ^ (lrow & 7)) * 8;
  const int fk1 = fk0 ^ 32;

  f32x4 acc[4][TN];
#pragma unroll
  for (int i = 0; i < 4; i++)
#pragma unroll
    for (int j = 0; j < TN; j++) acc[i][j] = (f32x4){0.f, 0.f, 0.f, 0.f};

  for (int k0 = 0; k0 < K; k0 += 64) {
    __syncthreads();
#pragma unroll
    for (int i = 0; i < 4; i++)
      gl2lds16(A + goffA[i] + k0, &As[(w * 4 + i) * 512]);
#pragma unroll
    for (int i = 0; i < NB; i++)
      gl2lds16(B + goffB[i] + k0, &Bs[(w * NB + i) * 512]);
    __syncthreads();

    s16x8 a[4][2], b[TN][2];
#pragma unroll
    for (int tm = 0; tm < 4; tm++) {
      a[tm][0] = *(const s16x8*)&As[(wm + tm * 16 + lrow) * 64 + fk0];
      a[tm][1] = *(const s16x8*)&As[(wm + tm * 16 + lrow) * 64 + fk1];
    }
#pragma unroll
    for (int tn = 0; tn < TN; tn++) {
      b[tn][0] = *(const s16x8*)&Bs[(wn + tn * 16 + lrow) * 64 + fk0];
      b[tn][1] = *(const s16x8*)&Bs[(wn + tn * 16 + lrow) * 64 + fk1];
    }
#pragma unroll
    for (int hh = 0; hh < 2; hh++)
#pragma unroll
      for (int tm = 0; tm < 4; tm++)
#pragma unroll
        for (int tn = 0; tn < TN; tn++)
          acc[tm][tn] = __builtin_amdgcn_mfma_f32_16x16x32_bf16(
              a[tm][hh], b[tn][hh], acc[tm][tn], 0, 0, 0);
  }

  if (MODE == 1) {
#pragma unroll
    for (int tm = 0; tm < 4; tm++)
#pragma unroll
      for (int tn = 0; tn < TN; tn++)
#pragma unroll
        for (int i = 0; i < 4; i++) {
          int row = bm + wm + tm * 16 + quad * 4 + i;
          int col = bn + wn + tn * 16 + lrow;
          ((float*)Cp)[(size_t)row * N + col] = acc[tm][tn][i] + bias[col];
        }
  } else if (bn < 2 * CDIM) {
#pragma unroll
    for (int tm = 0; tm < 4; tm++)
#pragma unroll
      for (int tn = 0; tn < TN; tn++)
#pragma unroll
        for (int i = 0; i < 4; i++) {
          int row = bm + wm + tm * 16 + quad * 4 + i;
          int col = bn + wn + tn * 16 + lrow;
          ((short*)Cp)[(size_t)row * 2048 + col] = f2bf(acc[tm][tn][i]);
        }
  } else {
#pragma unroll
    for (int tm = 0; tm < 4; tm++)
#pragma unroll
      for (int tn = 0; tn < TN; tn++) {
        int vcol = bn - 2 * CDIM + wn + tn * 16 + lrow;
        int h    = vcol >> 6, d = vcol & 63;
        int r0   = bm + wm + tm * 16 + quad * 4;
        int bb   = r0 >> 11, key = r0 & (SEQ - 1);
        size_t off = (((size_t)(bb * NH + h) * HD + d) << 11) + key;
        uint2 pk;
        pk.x = f2bf2(acc[tm][tn][0], acc[tm][tn][1]);
        pk.y = f2bf2(acc[tm][tn][2], acc[tm][tn][3]);
        *(uint2*)(vt + off) = pk;
      }
  }
}

// ---------------------------------------------------------------------------
// Flash attention (r11 verbatim). 32x32x16 MFMA, 2x2 wave grid (wq=q-half,
// wk=key-half). Register prefetch: chunk n+1's K/V global loads issue right
// after barrier 2 and overlap chunk n's compute; single LDS buffer, pitch 72
// (144 B: 16B-aligned, conflict-free b128 frag reads); staging lane-quad
// coalesced (4 lanes/row = 128B segments). S^T = mfma(K, Q(regs)); C->A via
// shfl_xor(32) in regs; no-max softmax (exp2, scale pre-folded).
// End: cross-wk O/l reduce via LDS.
// ---------------------------------------------------------------------------
__global__ __launch_bounds__(256) void attn_kernel(
    const short* __restrict__ qk, const short* __restrict__ vt,
    short* __restrict__ attn_out)
{
  __shared__ __align__(16) short smem[2 * 64 * 72];   // Ks | Vs, 18 KB
  short* Ks = smem;
  short* Vs = smem + 64 * 72;

  const int t   = threadIdx.x;
  const int w   = t >> 6, lane = t & 63;
  const int l31 = lane & 31, h = lane >> 5;
  const int wq  = w & 1, wk = w >> 1;
  const int bh  = blockIdx.x;
  const int b   = bh >> 4, hd = bh & (NH - 1);
  const int q0  = blockIdx.y * 64;

  const short* base  = qk + (size_t)(b * SEQ) * 2048 + hd * HD;
  const short* vbase = vt + ((size_t)(b * NH + hd) * HD) * SEQ;

  // Q B-frags in registers (pre-scaled): n=q, k=d=c*16+h*8+j
  s16x8 qf[4];
  {
    const short* qp = base + (size_t)(q0 + wq * 32 + l31) * 2048;
#pragma unroll
    for (int c = 0; c < 4; c++) qf[c] = *(const s16x8*)(qp + c * 16 + h * 8);
  }

  f32x16 o0 = {}, o1 = {};
  float lsum = 0.f;

  const int kr = t >> 2, kc = (t & 3) * 16;   // staging: 64 rows x 64, 16/thr

  // prefetch chunk 0 into registers
  s16x8 pk0, pk1, pv0, pv1;
  {
    const short* kp = base + (size_t)kr * 2048 + CDIM + kc;
    pk0 = *(const s16x8*)kp; pk1 = *(const s16x8*)(kp + 8);
    const short* vp = vbase + (size_t)kr * SEQ + kc;
    pv0 = *(const s16x8*)vp; pv1 = *(const s16x8*)(vp + 8);
  }

  for (int n0 = 0; n0 < SEQ; n0 += 64) {
    __syncthreads();                          // prior chunk's frag reads done
    *(s16x8*)&Ks[kr * 72 + kc]     = pk0;
    *(s16x8*)&Ks[kr * 72 + kc + 8] = pk1;
    *(s16x8*)&Vs[kr * 72 + kc]     = pv0;
    *(s16x8*)&Vs[kr * 72 + kc + 8] = pv1;
    __syncthreads();                          // tiles ready

    // issue next chunk's loads (overlap with compute below)
    {
      int nn = (n0 + 64 < SEQ) ? n0 + 64 : n0;
      const short* kp = base + (size_t)(nn + kr) * 2048 + CDIM + kc;
      pk0 = *(const s16x8*)kp; pk1 = *(const s16x8*)(kp + 8);
      const short* vp = vbase + (size_t)kr * SEQ + nn + kc;
      pv0 = *(const s16x8*)vp; pv1 = *(const s16x8*)(vp + 8);
    }

    // S^T[key][q]: A = K rows (wk half), B = Q regs
    f32x16 s = {};
#pragma unroll
    for (int c = 0; c < 4; c++) {
      s16x8 kf = *(const s16x8*)&Ks[(wk * 32 + l31) * 72 + c * 16 + h * 8];
      s = __builtin_amdgcn_mfma_f32_32x32x16_bf16(kf, qf[c], s, 0, 0, 0);
    }

    // softmax + pack: reg r -> key (r&3)+8*(r>>2)+4h (local to wave's half)
    uint2 pg[4];
#pragma unroll
    for (int g = 0; g < 4; g++) {
      float p0 = exp2_fast(s[4 * g + 0]);
      float p1 = exp2_fast(s[4 * g + 1]);
      float p2 = exp2_fast(s[4 * g + 2]);
      float p3 = exp2_fast(s[4 * g + 3]);
      lsum += (p0 + p1) + (p2 + p3);
      pg[g].x = f2bf2(p0, p1);
      pg[g].y = f2bf2(p2, p3);
    }

    // C->A: per 16-key chunk kc2, swap 4-key groups between lane<->lane+32
    s16x8 pf[2];
#pragma unroll
    for (int kc2 = 0; kc2 < 2; kc2++) {
      uint2 send = h ? pg[2 * kc2] : pg[2 * kc2 + 1];
      uint2 recv;
      recv.x = (unsigned)__shfl_xor((int)send.x, 32);
      recv.y = (unsigned)__shfl_xor((int)send.y, 32);
      uint2 lo = h ? recv : pg[2 * kc2];
      uint2 hi = h ? pg[2 * kc2 + 1] : recv;
      u32x4 f = {lo.x, lo.y, hi.x, hi.y};
      pf[kc2] = __builtin_bit_cast(s16x8, f);
    }

    // PV: O[q][d] += P * V over wave's 32 keys; B-frag from Vs[d][key]
#pragma unroll
    for (int kc2 = 0; kc2 < 2; kc2++) {
      s16x8 v0 = *(const s16x8*)&Vs[l31 * 72        + wk * 32 + kc2 * 16 + h * 8];
      s16x8 v1 = *(const s16x8*)&Vs[(32 + l31) * 72 + wk * 32 + kc2 * 16 + h * 8];
      o0 = __builtin_amdgcn_mfma_f32_32x32x16_bf16(pf[kc2], v0, o0, 0, 0, 0);
      o1 = __builtin_amdgcn_mfma_f32_32x32x16_bf16(pf[kc2], v1, o1, 0, 0, 0);
    }
  }

  // ---- epilogue: cross-wk reduction of O and l, normalize, store ----
  lsum += __shfl_xor(lsum, 32);          // combine h halves (disjoint keys)

  float* Ored = (float*)smem;            // [2 wq][32 q][64 d] = 16 KB
  float* Lred = (float*)smem + 4096;     // [64]

  __syncthreads();                       // drain last chunk's LDS reads
  if (wk == 0) {
#pragma unroll
    for (int r = 0; r < 16; r++) {
      int ql = (r & 3) + 8 * (r >> 2) + 4 * h;
      Ored[(wq * 32 + ql) * 64 + l31]      = o0[r];
      Ored[(wq * 32 + ql) * 64 + 32 + l31] = o1[r];
    }
    if (lane < 32) Lred[wq * 32 + l31] = lsum;
  }
  __syncthreads();
  if (wk == 1 && lane < 32) Lred[wq * 32 + l31] += lsum;
  __syncthreads();
  if (wk == 1) {
#pragma unroll
    for (int r = 0; r < 16; r++) {
      int ql = (r & 3) + 8 * (r >> 2) + 4 * h;
      float linv = 1.0f / Lred[wq * 32 + ql];
      int qg = q0 + wq * 32 + ql;
      size_t rowb = (size_t)(b * SEQ + qg) * CDIM + hd * HD;
      float v0 = (o0[r] + Ored[(wq * 32 + ql) * 64 + l31]) * linv;
      float v1 = (o1[r] + Ored[(wq * 32 + ql) * 64 + 32 + l31]) * linv;
      attn_out[rowb + l31]      = f2bf(v0);
      attn_out[rowb + 32 + l31] = f2bf(v1);
    }
  }
}

// ---------------------------------------------------------------------------
extern "C" void kernel_launch(void* const* d_in, const int* in_sizes, int n_in,
                              void* d_out, int out_size, void* d_ws, size_t ws_size,
                              hipStream_t stream)
{
  const float* x     = (const float*)d_in[0];
  const float* w_qkv = (const float*)d_in[1];
  const float* w_out = (const float*)d_in[2];
  const float* b_out = (const float*)d_in[3];

  short* qk_ws   = (short*)d_ws;                         // 4096*2048 = 16 MB
  short* vt_ws   = qk_ws  + (size_t)NTOK * 2048;         // 4096*1024 =  8 MB
  short* x_bf    = vt_ws  + (size_t)NTOK * CDIM;         // 4096*1024 =  8 MB
  short* attn_ws = x_bf;                                 // alias (x_bf dead)
  short* wqkv_bf = x_bf   + (size_t)NTOK * CDIM;         // 3072*1024 =  6 MB
  short* wout_bf = wqkv_bf + (size_t)3 * CDIM * CDIM;    // 1024*1024 =  2 MB

  dim3 blk(256);

  cvt_all<<<dim3(4096), blk, 0, stream>>>(x, w_qkv, w_out, x_bf, wqkv_bf, wout_bf);

  // (1) qkv: 768 blocks, 1-D XCD-swizzled (3 B-panels per XCD)
  gemm128<0, 128, 3><<<dim3(768), blk, 0, stream>>>(
      x_bf, wqkv_bf, nullptr, qk_ws, vt_ws, NTOK, 3 * CDIM, CDIM);

  attn_kernel<<<dim3(BATCH * NH, SEQ / 64), blk, 0, stream>>>(qk_ws, vt_ws, attn_ws);

  // (3) out: 512 blocks, 1-D XCD-swizzled (2 B-panels per XCD)
  gemm128<1, 64, 2><<<dim3(512), blk, 0, stream>>>(
      attn_ws, wout_bf, b_out, d_out, nullptr, NTOK, CDIM, CDIM);
}